// Round 2
// baseline (284.925 us; speedup 1.0000x reference)
//
#include <hip/hip_runtime.h>

// SoftDepthShader: softmax depth blend, N=8 H=256 W=256 K=50 (524288 pixels).
// ~315 MB read, ~2 MB write -> memory-bound. R3 measured 1.45 TB/s (18% HBM),
// VGPR_Count=20: the RP-minimizing scheduler sank the 12x8B loads into ~3-load
// batches => ~2 KB in flight per wave, Little's-law-capped BW.
//
// R5 = dual-pixel R3 (latency fix with zero remapping risk):
//   - Each 8-lane team processes TWO adjacent pixels; each pixel uses R3's
//     exact proven pipeline (float2 chunks {q, q+8, q+16} + uniform tail
//     chunk 24 gated to lane q==0). No cross-pixel element routing (the R4
//     pair-split failed correctness and was reverted).
//   - ALL 24 loads (f/z/d x 4 chunks x 2 pixels) issued first, then
//     __builtin_amdgcn_sched_barrier(0): loads cannot sink below uses, so
//     192 B/thread = 12 KB/wave stay in flight.
//   - __launch_bounds__(256, 4): VGPR target 128 so the scheduler stops
//     register-minimizing the load phase (expect ~60-85 VGPRs).

constexpr int THREADS = 256;
constexpr int LPP     = 8;               // lanes per team
constexpr int TPB     = THREADS / LPP;   // 32 teams per block, 2 pixels each

constexpr float INV_SIGMA  = 1e4f;       // 1/sigma
constexpr float INVG       = 1e4f;       // 1/gamma
constexpr float ZFAR       = 100.0f;
constexpr float ZRANGE     = 99.0f;      // zfar - znear
constexpr float INV_ZRANGE = 1.0f / 99.0f;
constexpr float EPS        = 1e-10f;

// R3's proven per-pixel pipeline, verbatim: masks -> masked z_inv/prob ->
// team max (tree + 3-step xor shuffle) -> weight sums -> shuffle-add.
__device__ __forceinline__ void pixel_blend(
    const int2 fa, const int2 fb, const int2 fc, const int2 fd,
    const float2 za, const float2 zb, const float2 zc, const float2 zd,
    const float2 da, const float2 db, const float2 dc, const float2 dd,
    const bool tail_owner,                      // q == 0 owns tail chunk 24
    float& m_out, float& s1_out, float& s2_out)
{
    const bool m0 = (fa.x >= 0),               m1 = (fa.y >= 0);
    const bool m2 = (fb.x >= 0),               m3 = (fb.y >= 0);
    const bool m4 = (fc.x >= 0),               m5 = (fc.y >= 0);
    const bool m6 = tail_owner && (fd.x >= 0), m7 = tail_owner && (fd.y >= 0);

    float zv[8], pv[8];
    zv[0] = m0 ? (ZFAR - za.x) * INV_ZRANGE : 0.0f;
    zv[1] = m1 ? (ZFAR - za.y) * INV_ZRANGE : 0.0f;
    zv[2] = m2 ? (ZFAR - zb.x) * INV_ZRANGE : 0.0f;
    zv[3] = m3 ? (ZFAR - zb.y) * INV_ZRANGE : 0.0f;
    zv[4] = m4 ? (ZFAR - zc.x) * INV_ZRANGE : 0.0f;
    zv[5] = m5 ? (ZFAR - zc.y) * INV_ZRANGE : 0.0f;
    zv[6] = m6 ? (ZFAR - zd.x) * INV_ZRANGE : 0.0f;
    zv[7] = m7 ? (ZFAR - zd.y) * INV_ZRANGE : 0.0f;
    pv[0] = m0 ? 1.0f / (1.0f + __expf(da.x * INV_SIGMA)) : 0.0f;
    pv[1] = m1 ? 1.0f / (1.0f + __expf(da.y * INV_SIGMA)) : 0.0f;
    pv[2] = m2 ? 1.0f / (1.0f + __expf(db.x * INV_SIGMA)) : 0.0f;
    pv[3] = m3 ? 1.0f / (1.0f + __expf(db.y * INV_SIGMA)) : 0.0f;
    pv[4] = m4 ? 1.0f / (1.0f + __expf(dc.x * INV_SIGMA)) : 0.0f;
    pv[5] = m5 ? 1.0f / (1.0f + __expf(dc.y * INV_SIGMA)) : 0.0f;
    pv[6] = m6 ? 1.0f / (1.0f + __expf(dd.x * INV_SIGMA)) : 0.0f;
    pv[7] = m7 ? 1.0f / (1.0f + __expf(dd.y * INV_SIGMA)) : 0.0f;

    float m = fmaxf(fmaxf(fmaxf(zv[0], zv[1]), fmaxf(zv[2], zv[3])),
                    fmaxf(fmaxf(zv[4], zv[5]), fmaxf(zv[6], zv[7])));
    m = fmaxf(m, __shfl_xor(m, 1));
    m = fmaxf(m, __shfl_xor(m, 2));
    m = fmaxf(m, __shfl_xor(m, 4));
    m = fmaxf(m, EPS);                   // reference: max(max_k z_inv, EPS)

    float S1a = 0.0f, S1b = 0.0f, S2a = 0.0f, S2b = 0.0f;
    #pragma unroll
    for (int j = 0; j < 8; j += 2) {
        const float w0 = pv[j]   * __expf((zv[j]   - m) * INVG);
        const float w1 = pv[j+1] * __expf((zv[j+1] - m) * INVG);
        S1a += w0;
        S1b += w1;
        S2a += w0 * (ZFAR - zv[j]   * ZRANGE);   // reconstruct zbuf; w==0 where masked
        S2b += w1 * (ZFAR - zv[j+1] * ZRANGE);
    }
    float S1 = S1a + S1b;
    float S2 = S2a + S2b;
    S1 += __shfl_xor(S1, 1);  S1 += __shfl_xor(S1, 2);  S1 += __shfl_xor(S1, 4);
    S2 += __shfl_xor(S2, 1);  S2 += __shfl_xor(S2, 2);  S2 += __shfl_xor(S2, 4);

    m_out = m;  s1_out = S1;  s2_out = S2;
}

__global__ __launch_bounds__(THREADS, 4) void soft_depth_kernel(
    const float* __restrict__ zbuf,
    const float* __restrict__ dists,
    const int*   __restrict__ p2f,
    float*       __restrict__ out)
{
    const int t = threadIdx.x;
    const int q = t & (LPP - 1);
    const size_t team = (size_t)blockIdx.x * TPB + (t >> 3);
    const size_t pix0 = 2 * team;            // this team's two pixels
    const size_t cbA  = pix0 * 25;           // float2-chunk base, pixel A
    const size_t cbB  = cbA + 25;            // pixel B (adjacent, +200 B)

    const float2* __restrict__ z2 = (const float2*)zbuf;
    const float2* __restrict__ d2 = (const float2*)dists;
    const int2*   __restrict__ f2 = (const int2*)p2f;

    const size_t a0 = cbA + q, a1 = cbA + q + 8, a2 = cbA + q + 16, a3 = cbA + 24;
    const size_t b0 = cbB + q, b1 = cbB + q + 8, b2 = cbB + q + 16, b3 = cbB + 24;

    // ---- phase 1: issue ALL 24 loads (consumption order: f, z, d) ----
    const int2   fA0 = f2[a0], fA1 = f2[a1], fA2 = f2[a2], fA3 = f2[a3];
    const int2   fB0 = f2[b0], fB1 = f2[b1], fB2 = f2[b2], fB3 = f2[b3];
    const float2 zA0 = z2[a0], zA1 = z2[a1], zA2 = z2[a2], zA3 = z2[a3];
    const float2 zB0 = z2[b0], zB1 = z2[b1], zB2 = z2[b2], zB3 = z2[b3];
    const float2 dA0 = d2[a0], dA1 = d2[a1], dA2 = d2[a2], dA3 = d2[a3];
    const float2 dB0 = d2[b0], dB1 = d2[b1], dB2 = d2[b2], dB3 = d2[b3];
    __builtin_amdgcn_sched_barrier(0);       // loads may not sink below here

    const bool town = (q == 0);
    float mA, S1A, S2A, mB, S1B, S2B;
    pixel_blend(fA0, fA1, fA2, fA3, zA0, zA1, zA2, zA3,
                dA0, dA1, dA2, dA3, town, mA, S1A, S2A);
    pixel_blend(fB0, fB1, fB2, fB3, zB0, zB1, zB2, zB3,
                dB0, dB1, dB2, dB3, town, mB, S1B, S2B);

    if (q < 2) {
        const float m  = (q == 0) ? mA  : mB;
        const float s1 = (q == 0) ? S1A : S1B;
        const float s2 = (q == 0) ? S2A : S2B;
        const float delta = fmaxf(__expf((EPS - m) * INVG), EPS);
        out[pix0 + (size_t)q] = (s2 + delta) / (s1 + delta);  // BG_BLUE = 1
    }
}

extern "C" void kernel_launch(void* const* d_in, const int* in_sizes, int n_in,
                              void* d_out, int out_size, void* d_ws, size_t ws_size,
                              hipStream_t stream) {
    const float* zbuf  = (const float*)d_in[0];
    const float* dists = (const float*)d_in[1];
    const int*   p2f   = (const int*)d_in[2];
    float* out = (float*)d_out;

    const int pixels = out_size;                 // 524288
    const int teams  = pixels / 2;               // 262144
    const int blocks = teams / TPB;              // 8192 (exact)

    soft_depth_kernel<<<dim3(blocks), dim3(THREADS), 0, stream>>>(
        zbuf, dists, p2f, out);
}